// Round 11
// baseline (115.200 us; speedup 1.0000x reference)
//
#include <hip/hip_runtime.h>

#define KW   7
#define CIN  64
#define COUT 64
#define HH   64
#define WW   64
#define BB   4
#define HW   (HH * WW)

// ===== DIAGNOSTIC ROUND: REP loops amplify each kernel above the rocprof
// top-5 cutoff (44us poison fills) to capture true per-kernel counters.
// Each rep recomputes and rewrites identical values (idempotent). =====
#define REP1 16
#define REP2 8

typedef __attribute__((ext_vector_type(8))) short short8v;  // 8 bf16
typedef __attribute__((ext_vector_type(4))) float f32x4;

__device__ __forceinline__ unsigned pack_bf16(float lo, float hi) {
    unsigned a = __builtin_bit_cast(unsigned, lo);
    unsigned b = __builtin_bit_cast(unsigned, hi);
    a = (a + 0x7fffu + ((a >> 16) & 1u)) >> 16;   // RNE f32->bf16
    b = (b + 0x7fffu + ((b >> 16) & 1u)) >> 16;
    return a | (b << 16);
}

// ---------------------------------------------------------------------------
// K1: q/k/v projection as bf16 MFMA GEMM (R9/R10 version), body looped REP1x.
// ---------------------------------------------------------------------------
#define LWROW 36   // dwords per LDS row (32 bf16-pairs padded)

__global__ __launch_bounds__(256) void projK(
    const float* __restrict__ x,  const float* __restrict__ wq,
    const float* __restrict__ wk, const float* __restrict__ wv,
    float* __restrict__ qb, float* __restrict__ kb, float* __restrict__ vb)
{
    __shared__ unsigned lw[48 * LWROW];
    __shared__ unsigned xt[64 * LWROW];

    const int tid = threadIdx.x;
    const int p0  = blockIdx.x * 64;
    const int mq  = blockIdx.y;
    const int b   = blockIdx.z;

    for (int rep = 0; rep < REP1; ++rep) {
        const float* wsel[3] = {wq, wk, wv};
        for (int idx = tid; idx < 48 * 32; idx += 256) {
            const int r  = idx >> 5;
            const int dw = idx & 31;
            const int g  = mq * 48 + r;
            const float* wr = wsel[g >> 6] + (g & 63) * CIN + dw * 2;
            lw[r * LWROW + dw] = pack_bf16(wr[0], wr[1]);
        }
        {
            const int p = tid & 63, grp = tid >> 6;
            const float* xb = x + (size_t)b * CIN * HW + p0 + p;
            #pragma unroll
            for (int d = 0; d < 8; ++d) {
                const int dw = grp * 8 + d;
                xt[p * LWROW + dw] =
                    pack_bf16(xb[(size_t)(2 * dw) * HW], xb[(size_t)(2 * dw + 1) * HW]);
            }
        }
        __syncthreads();

        const int lane = tid & 63;
        const int wid  = tid >> 6;
        const int col  = lane & 15;
        const int lg   = lane >> 4;
        const int n0   = wid * 16;

        short8v bfrag[2];
        #pragma unroll
        for (int kc = 0; kc < 2; ++kc)
            bfrag[kc] = *(const short8v*)&xt[(n0 + col) * LWROW + kc * 16 + lg * 4];

        float* osel[3] = {qb, kb, vb};
        #pragma unroll
        for (int t = 0; t < 3; ++t) {
            f32x4 acc = {0.f, 0.f, 0.f, 0.f};
            #pragma unroll
            for (int kc = 0; kc < 2; ++kc) {
                const short8v afrag =
                    *(const short8v*)&lw[(t * 16 + col) * LWROW + kc * 16 + lg * 4];
                acc = __builtin_amdgcn_mfma_f32_16x16x32_bf16(afrag, bfrag[kc], acc, 0, 0, 0);
            }
            const int g0  = mq * 48 + t * 16;
            const int mat = g0 >> 6;
            const int chb = (g0 & 63) + lg * 4;
            float* dst = osel[mat] + ((size_t)b * COUT + chb) * HW + p0 + n0 + col;
            #pragma unroll
            for (int r = 0; r < 4; ++r) dst[(size_t)r * HW] = acc[r];
        }
        __syncthreads();   // protect LDS before next rep's restage
    }
}

// ---------------------------------------------------------------------------
// K2: 7x7 local attention (R10 2-row register-blocked version), looped REP2x.
// ---------------------------------------------------------------------------
#define TRO  8             // output rows per block
#define SRO  (TRO + 6)     // 14 staged rows

template <bool USE_H>
__device__ __forceinline__ void attn_rows(
    const float2 (*kv)[70], const float q2[2], const float qadd[2][KW],
    int tx, int r0, float s[2], float acc[2])
{
    #pragma unroll
    for (int rr = 0; rr < 8; ++rr) {
        float2 kvx[KW];
        #pragma unroll
        for (int j = 0; j < KW; ++j) kvx[j] = kv[r0 + rr][tx + j];

        if (rr <= 6) {
            #pragma unroll
            for (int j = 0; j < KW; ++j) {
                const float e = __builtin_amdgcn_exp2f(
                    fmaf(q2[0], kvx[j].x, qadd[0][USE_H ? rr : j]));
                s[0] += e;
                acc[0] = fmaf(e, kvx[j].y, acc[0]);
            }
        }
        if (rr >= 1) {
            #pragma unroll
            for (int j = 0; j < KW; ++j) {
                const float e = __builtin_amdgcn_exp2f(
                    fmaf(q2[1], kvx[j].x, qadd[1][USE_H ? (rr - 1) : j]));
                s[1] += e;
                acc[1] = fmaf(e, kvx[j].y, acc[1]);
            }
        }
    }
}

__global__ __launch_bounds__(256) void attnK(
    const float* __restrict__ qb, const float* __restrict__ kb,
    const float* __restrict__ vb, const float* __restrict__ rel_h,
    const float* __restrict__ rel_w, float* __restrict__ out)
{
    __shared__ float2 kv[SRO][70];

    const int tx = threadIdx.x;
    const int ty = threadIdx.y;
    const int h0 = blockIdx.x * TRO;
    const int o  = blockIdx.y;
    const int b  = blockIdx.z;
    const size_t plane = ((size_t)b * COUT + o) * HW;

    for (int rep = 0; rep < REP2; ++rep) {
        for (int idx = ty * 64 + tx; idx < SRO * 70; idx += 256) {
            const int rr = idx / 70;
            const int sc = idx - rr * 70;
            const int gr = h0 - 3 + rr;
            const int gc = sc - 3;
            float kk = 0.f, vv = 0.f;
            if (((unsigned)gr < HH) & ((unsigned)gc < WW)) {
                kk = kb[plane + (size_t)gr * WW + gc];
                vv = vb[plane + (size_t)gr * WW + gc];
            }
            kv[rr][sc] = make_float2(kk, vv);
        }
        __syncthreads();

        const int r0 = 2 * ty;

        float q2[2];
        #pragma unroll
        for (int r = 0; r < 2; ++r)
            q2[r] = qb[plane + (size_t)(h0 + r0 + r) * WW + tx] * 1.44269504088896f;

        const bool use_h = (o < COUT / 2);
        const float* rp = use_h ? (rel_h + o * KW) : (rel_w + (o - COUT / 2) * KW);
        float qadd[2][KW];
        #pragma unroll
        for (int t = 0; t < KW; ++t) {
            const float rv = rp[t];
            qadd[0][t] = q2[0] * rv;
            qadd[1][t] = q2[1] * rv;
        }

        float s[2]   = {0.f, 0.f};
        float acc[2] = {0.f, 0.f};
        if (use_h) attn_rows<true >(kv, q2, qadd, tx, r0, s, acc);
        else       attn_rows<false>(kv, q2, qadd, tx, r0, s, acc);

        #pragma unroll
        for (int r = 0; r < 2; ++r)
            out[plane + (size_t)(h0 + r0 + r) * WW + tx] =
                acc[r] * __builtin_amdgcn_rcpf(s[r]);
        __syncthreads();   // protect LDS before next rep's restage
    }
}

extern "C" void kernel_launch(void* const* d_in, const int* in_sizes, int n_in,
                              void* d_out, int out_size, void* d_ws, size_t ws_size,
                              hipStream_t stream) {
    const float* x     = (const float*)d_in[0];
    const float* wq    = (const float*)d_in[1];
    const float* wk    = (const float*)d_in[2];
    const float* wv    = (const float*)d_in[3];
    const float* rel_h = (const float*)d_in[4];
    const float* rel_w = (const float*)d_in[5];
    float* out = (float*)d_out;

    float* qb = (float*)d_ws;
    float* kb = qb + (size_t)BB * COUT * HW;
    float* vb = kb + (size_t)BB * COUT * HW;

    dim3 g1(HW / 64, 4, BB);                  // (64, 4, 4) = 1024 blocks
    projK<<<g1, 256, 0, stream>>>(x, wq, wk, wv, qb, kb, vb);

    dim3 g2(HH / TRO, COUT, BB);              // (8, 64, 4) = 2048 blocks
    dim3 b2(64, 4);
    attnK<<<g2, b2, 0, stream>>>(qb, kb, vb, rel_h, rel_w, out);
}

// Round 13
// 26.512 us; speedup vs baseline: 4.3452x; 4.3452x over previous
//
#include <hip/hip_runtime.h>

#define KW   7
#define CIN  64
#define COUT 64
#define HH   64
#define WW   64
#define BB   4
#define HW   (HH * WW)

typedef __attribute__((ext_vector_type(8))) short  short8v;   // 8 bf16
typedef __attribute__((ext_vector_type(4))) float  f32x4;
typedef __attribute__((ext_vector_type(4))) unsigned u32x4;

__device__ __forceinline__ unsigned pack_bf16(float lo, float hi) {
    unsigned a = __builtin_bit_cast(unsigned, lo);
    unsigned b = __builtin_bit_cast(unsigned, hi);
    a = (a + 0x7fffu + ((a >> 16) & 1u)) >> 16;   // RNE f32->bf16
    b = (b + 0x7fffu + ((b >> 16) & 1u)) >> 16;
    return a | (b << 16);
}

// ---------------------------------------------------------------------------
// projK': BISECT KERNEL — R12's phase-1 GEMM variant, but writing to GLOBAL.
// Block = 4 channels x 8 rows x b (512 blocks). Stacked W rows: 0-3 wq,
// 4-7 wk, 8-11 wv (channels c0..c0+3), 12-15 zero. M=16, K=64, N=8rows x 64px.
// B-fragments packed in-register from global x (channel order = kc*32+lg*8+e,
// identical to R9's proven xt path). C layout m89: m=(lane>>4)*4+reg -> lg0
// lanes carry q rows, lg1 k rows, lg2 v rows; n=lane&15 -> pixel quad*16+col.
// k/v written interleaved (float2 kvb) so attnK' stages with single b64 loads.
// If this fails, R12's GEMM arrangement is the bug; if it passes, it wasn't.
// ---------------------------------------------------------------------------
#define LWROW 36

__global__ __launch_bounds__(256) void projK(
    const float* __restrict__ x,  const float* __restrict__ wq,
    const float* __restrict__ wk, const float* __restrict__ wv,
    float* __restrict__ qb, float2* __restrict__ kvb)
{
    __shared__ unsigned lw[16 * LWROW];

    const int tid  = threadIdx.x;
    const int lane = tid & 63;
    const int wid  = tid >> 6;
    const int h0   = blockIdx.x * 8;          // 8 rows, no halo
    const int c0   = blockIdx.y * 4;
    const int b    = blockIdx.z;

    const float* wsel[3] = {wq, wk, wv};
    for (int idx = tid; idx < 16 * 32; idx += 256) {
        const int r  = idx >> 5;
        const int dw = idx & 31;
        unsigned v = 0u;
        if (r < 12) {
            const float* wr = wsel[r >> 2] + (c0 + (r & 3)) * CIN + dw * 2;
            v = pack_bf16(wr[0], wr[1]);
        }
        lw[r * LWROW + dw] = v;
    }
    __syncthreads();

    const int col = lane & 15;
    const int lg  = lane >> 4;

    short8v afrag[2];
    #pragma unroll
    for (int kc = 0; kc < 2; ++kc)
        afrag[kc] = *(const short8v*)&lw[col * LWROW + kc * 16 + lg * 4];

    const float* xb = x + (size_t)b * CIN * HW;
    for (int n = wid; n < 32; n += 4) {       // 8 rows x 4 quads
        const int sr   = n >> 2;
        const int quad = n & 3;
        const int gr   = h0 + sr;

        const float* xp = xb + (size_t)gr * WW + quad * 16 + col;
        f32x4 acc = {0.f, 0.f, 0.f, 0.f};
        #pragma unroll
        for (int kc = 0; kc < 2; ++kc) {
            u32x4 bd;
            #pragma unroll
            for (int i = 0; i < 4; ++i) {
                const int ch = kc * 32 + lg * 8 + 2 * i;
                bd[i] = pack_bf16(xp[(size_t)ch * HW], xp[(size_t)(ch + 1) * HW]);
            }
            acc = __builtin_amdgcn_mfma_f32_16x16x32_bf16(
                afrag[kc], __builtin_bit_cast(short8v, bd), acc, 0, 0, 0);
        }

        const size_t ppos = (size_t)gr * WW + quad * 16 + col;
        if (lg == 0) {
            #pragma unroll
            for (int r = 0; r < 4; ++r)
                qb[(size_t)(b * COUT + c0 + r) * HW + ppos] = acc[r];
        } else if (lg == 1) {
            #pragma unroll
            for (int r = 0; r < 4; ++r)
                kvb[(size_t)(b * COUT + c0 + r) * HW + ppos].x = acc[r];
        } else if (lg == 2) {
            #pragma unroll
            for (int r = 0; r < 4; ++r)
                kvb[(size_t)(b * COUT + c0 + r) * HW + ppos].y = acc[r];
        }
    }
}

// ---------------------------------------------------------------------------
// attnK': R10's PASSING attention kernel; only the stage loop changed to read
// the interleaved kvb with a single float2 load per element. Everything else
// (geometry, 2-row register blocking, no-max softmax, rel template) is
// byte-identical to the 27.1us baseline.
// ---------------------------------------------------------------------------
#define TRO  8             // output rows per block
#define SRO  (TRO + 6)     // 14 staged rows

template <bool USE_H>
__device__ __forceinline__ void attn_rows(
    const float2 (*kv)[70], const float q2[2], const float qadd[2][KW],
    int tx, int r0, float s[2], float acc[2])
{
    #pragma unroll
    for (int rr = 0; rr < 8; ++rr) {
        float2 kvx[KW];
        #pragma unroll
        for (int j = 0; j < KW; ++j) kvx[j] = kv[r0 + rr][tx + j];

        if (rr <= 6) {
            #pragma unroll
            for (int j = 0; j < KW; ++j) {
                const float e = __builtin_amdgcn_exp2f(
                    fmaf(q2[0], kvx[j].x, qadd[0][USE_H ? rr : j]));
                s[0] += e;
                acc[0] = fmaf(e, kvx[j].y, acc[0]);
            }
        }
        if (rr >= 1) {
            #pragma unroll
            for (int j = 0; j < KW; ++j) {
                const float e = __builtin_amdgcn_exp2f(
                    fmaf(q2[1], kvx[j].x, qadd[1][USE_H ? (rr - 1) : j]));
                s[1] += e;
                acc[1] = fmaf(e, kvx[j].y, acc[1]);
            }
        }
    }
}

__global__ __launch_bounds__(256) void attnK(
    const float* __restrict__ qb, const float2* __restrict__ kvb,
    const float* __restrict__ rel_h, const float* __restrict__ rel_w,
    float* __restrict__ out)
{
    __shared__ float2 kv[SRO][70];

    const int tx = threadIdx.x;               // w: 0..63 (lane)
    const int ty = threadIdx.y;               // row pair: 0..3
    const int h0 = blockIdx.x * TRO;
    const int o  = blockIdx.y;
    const int b  = blockIdx.z;
    const size_t plane = ((size_t)b * COUT + o) * HW;

    // Stage rows h0-3 .. h0+10, cols -3..66, zeros outside the interior.
    for (int idx = ty * 64 + tx; idx < SRO * 70; idx += 256) {
        const int rr = idx / 70;
        const int sc = idx - rr * 70;
        const int gr = h0 - 3 + rr;
        const int gc = sc - 3;
        float2 kvv = make_float2(0.f, 0.f);
        if (((unsigned)gr < HH) & ((unsigned)gc < WW))
            kvv = kvb[plane + (size_t)gr * WW + gc];
        kv[rr][sc] = kvv;
    }
    __syncthreads();

    const int r0 = 2 * ty;                    // local output rows r0, r0+1

    float q2[2];
    #pragma unroll
    for (int r = 0; r < 2; ++r)
        q2[r] = qb[plane + (size_t)(h0 + r0 + r) * WW + tx] * 1.44269504088896f;

    const bool use_h = (o < COUT / 2);        // block-uniform
    const float* rp = use_h ? (rel_h + o * KW) : (rel_w + (o - COUT / 2) * KW);
    float qadd[2][KW];
    #pragma unroll
    for (int t = 0; t < KW; ++t) {
        const float rv = rp[t];
        qadd[0][t] = q2[0] * rv;
        qadd[1][t] = q2[1] * rv;
    }

    float s[2]   = {0.f, 0.f};
    float acc[2] = {0.f, 0.f};
    if (use_h) attn_rows<true >(kv, q2, qadd, tx, r0, s, acc);
    else       attn_rows<false>(kv, q2, qadd, tx, r0, s, acc);

    #pragma unroll
    for (int r = 0; r < 2; ++r)
        out[plane + (size_t)(h0 + r0 + r) * WW + tx] =
            acc[r] * __builtin_amdgcn_rcpf(s[r]);
}

extern "C" void kernel_launch(void* const* d_in, const int* in_sizes, int n_in,
                              void* d_out, int out_size, void* d_ws, size_t ws_size,
                              hipStream_t stream) {
    const float* x     = (const float*)d_in[0];
    const float* wq    = (const float*)d_in[1];
    const float* wk    = (const float*)d_in[2];
    const float* wv    = (const float*)d_in[3];
    const float* rel_h = (const float*)d_in[4];
    const float* rel_w = (const float*)d_in[5];
    float* out = (float*)d_out;

    float*  qb  = (float*)d_ws;                       // 4 MB
    float2* kvb = (float2*)(qb + (size_t)BB * COUT * HW);  // 8 MB interleaved k,v

    dim3 g1(HH / 8, COUT / 4, BB);            // (8, 16, 4) = 512 blocks
    projK<<<g1, 256, 0, stream>>>(x, wq, wk, wv, qb, kvb);

    dim3 g2(HH / TRO, COUT, BB);              // (8, 64, 4) = 2048 blocks
    dim3 b2(64, 4);
    attnK<<<g2, b2, 0, stream>>>(qb, kvb, rel_h, rel_w, out);
}

// Round 14
// 25.350 us; speedup vs baseline: 4.5444x; 1.0458x over previous
//
#include <hip/hip_runtime.h>

#define KW   7
#define CIN  64
#define COUT 64
#define HH   64
#define WW   64
#define BB   4
#define HW   (HH * WW)

#define NCH  4             // channels per block
#define TRO  8             // output rows per block
#define SRO  (TRO + 6)     // 14 staged k/v rows
#define LWROW 36           // W LDS row stride (dwords; 16B-aligned b128 frags)

typedef __attribute__((ext_vector_type(8))) short  short8v;   // 8 bf16
typedef __attribute__((ext_vector_type(4))) float  f32x4;
typedef __attribute__((ext_vector_type(4))) unsigned u32x4;

__device__ __forceinline__ unsigned pack_bf16(float lo, float hi) {
    unsigned a = __builtin_bit_cast(unsigned, lo);
    unsigned b = __builtin_bit_cast(unsigned, hi);
    a = (a + 0x7fffu + ((a >> 16) & 1u)) >> 16;   // RNE f32->bf16
    b = (b + 0x7fffu + ((b >> 16) & 1u)) >> 16;
    return a | (b << 16);
}

// ---------------------------------------------------------------------------
// Fused AttentionConv, rebuilt from the R13-proven pieces.
// Block = 4 channels x 8 output rows x 1 batch; 512 blocks x 512 threads
// (2 blocks/CU, 16 waves/CU). LDS 41 KB/block.
// Phase 1 (== R13 projK, proven): D[16 x 896] = Wstk[16 x 64] @ x[64 x 896].
//   Wstk rows 0-3 wq, 4-7 wk, 8-11 wv (channels c0..c0+3), 12-15 zero.
//   B-frags packed in-register from x with the same lane->k map as A
//   (permutation cancels; R9/R13-proven). C layout m89: n=lane&15 (pixel),
//   m=(lane>>4)*4+reg -> lg0 lanes route q (f32 LDS), lg1 k (.x), lg2 v (.y).
//   Halo rows outside [0,64) skipped -> kv stays zero (1x1 conv of zero pad
//   = 0, no bias). q rows (sr 3..10) always interior.
// Phase 2 (== R10/R13 attnK body, proven): wave = (channel, row-half);
//   2 row-pairs per wave, 2-row register blocking, aligned float2 LDS reads,
//   no-max softmax (logits bounded; bench-validated absmax<=0.068).
// No qkv global round-trip, no inter-kernel flush, one launch.
// ---------------------------------------------------------------------------
__global__ __launch_bounds__(512) void fusedK(
    const float* __restrict__ x,  const float* __restrict__ wq,
    const float* __restrict__ wk, const float* __restrict__ wv,
    const float* __restrict__ rel_h, const float* __restrict__ rel_w,
    float* __restrict__ out)
{
    __shared__ float2 kv[NCH][SRO][70];        // (k,v) interleaved, 31.4 KB
    __shared__ float  qtf[NCH][TRO][64];       // q as f32, 8 KB
    __shared__ unsigned lw[16 * LWROW];        // stacked W bf16 pairs, 2.3 KB

    const int tid  = threadIdx.x;
    const int lane = tid & 63;
    const int wid  = tid >> 6;                 // 0..7
    const int h0   = blockIdx.x * TRO;
    const int c0   = blockIdx.y * NCH;
    const int b    = blockIdx.z;

    // ---- zero-fill kv (halo rows/cols must stay exactly 0) ----
    {
        float2* kvf = &kv[0][0][0];
        for (int i = tid; i < NCH * SRO * 70; i += 512)
            kvf[i] = make_float2(0.f, 0.f);
    }
    // ---- stage stacked W (12 real rows + 4 zero): 512 slots, 1 per thread ----
    {
        const float* wsel[3] = {wq, wk, wv};
        const int r  = tid >> 5;               // 0..15
        const int dw = tid & 31;
        unsigned v = 0u;
        if (r < 12) {
            const float* wr = wsel[r >> 2] + (c0 + (r & 3)) * CIN + dw * 2;
            v = pack_bf16(wr[0], wr[1]);
        }
        lw[r * LWROW + dw] = v;
    }
    __syncthreads();

    // ---- Phase 1: MFMA projection into LDS ----
    const int col = lane & 15;
    const int lg  = lane >> 4;

    short8v afrag[2];
    #pragma unroll
    for (int kc = 0; kc < 2; ++kc)
        afrag[kc] = *(const short8v*)&lw[col * LWROW + kc * 16 + lg * 4];

    const float* xb = x + (size_t)b * CIN * HW;
    for (int n = wid; n < 4 * SRO; n += 8) {   // 56 (sr,quad) tiles / 8 waves
        const int sr   = n >> 2;               // staged row 0..13
        const int quad = n & 3;                // 16-px column group
        const int gr   = h0 - 3 + sr;          // global row (wave-uniform)
        if ((unsigned)gr >= HH) continue;      // halo row: kv stays zero

        const float* xp = xb + (size_t)gr * WW + quad * 16 + col;
        f32x4 acc = {0.f, 0.f, 0.f, 0.f};
        #pragma unroll
        for (int kc = 0; kc < 2; ++kc) {
            u32x4 bd;
            #pragma unroll
            for (int i = 0; i < 4; ++i) {
                const int ch = kc * 32 + lg * 8 + 2 * i;
                bd[i] = pack_bf16(xp[(size_t)ch * HW], xp[(size_t)(ch + 1) * HW]);
            }
            acc = __builtin_amdgcn_mfma_f32_16x16x32_bf16(
                afrag[kc], __builtin_bit_cast(short8v, bd), acc, 0, 0, 0);
        }

        const int pxc = quad * 16 + col;
        if (lg == 0) {                          // q channels c0..c0+3
            if (sr >= 3 && sr < 3 + TRO) {
                #pragma unroll
                for (int r = 0; r < 4; ++r) qtf[r][sr - 3][pxc] = acc[r];
            }
        } else if (lg == 1) {                   // k
            #pragma unroll
            for (int r = 0; r < 4; ++r) kv[r][sr][3 + pxc].x = acc[r];
        } else if (lg == 2) {                   // v
            #pragma unroll
            for (int r = 0; r < 4; ++r) kv[r][sr][3 + pxc].y = acc[r];
        }
    }
    __syncthreads();

    // ---- Phase 2: 7x7 local attention (wave = channel x row-half) ----
    const int tx   = lane;                     // output column
    const int ch   = wid >> 1;                 // 0..3
    const int half = wid & 1;                  // rows half*4 .. half*4+3
    const int o    = c0 + ch;
    const bool use_h = (o < COUT / 2);         // uniform within block

    float rel[KW];
    {
        const float* rp_ = use_h ? (rel_h + o * KW) : (rel_w + (o - COUT / 2) * KW);
        #pragma unroll
        for (int t = 0; t < KW; ++t) rel[t] = rp_[t];
    }
    const float2 (*kvp)[70] = kv[ch];
    const size_t obase = ((size_t)b * COUT + o) * HW;

    #pragma unroll
    for (int rp2 = 0; rp2 < 2; ++rp2) {
        const int r0 = (half * 2 + rp2) * 2;   // local out rows r0, r0+1

        float q2[2], qadd[2][KW];
        #pragma unroll
        for (int r = 0; r < 2; ++r) {
            q2[r] = qtf[ch][r0 + r][tx] * 1.44269504088896f;  // fold log2(e)
            #pragma unroll
            for (int t = 0; t < KW; ++t) qadd[r][t] = q2[r] * rel[t];
        }

        float s[2]   = {0.f, 0.f};
        float acc[2] = {0.f, 0.f};
        #pragma unroll
        for (int rr = 0; rr < 8; ++rr) {       // staged rows r0 .. r0+7
            float2 kvx[KW];
            #pragma unroll
            for (int j = 0; j < KW; ++j) kvx[j] = kvp[r0 + rr][tx + j];

            if (rr <= 6) {                     // out row r0: window row i = rr
                #pragma unroll
                for (int j = 0; j < KW; ++j) {
                    const float e = __builtin_amdgcn_exp2f(
                        fmaf(q2[0], kvx[j].x, use_h ? qadd[0][rr] : qadd[0][j]));
                    s[0] += e;
                    acc[0] = fmaf(e, kvx[j].y, acc[0]);
                }
            }
            if (rr >= 1) {                     // out row r0+1: window row rr-1
                #pragma unroll
                for (int j = 0; j < KW; ++j) {
                    const float e = __builtin_amdgcn_exp2f(
                        fmaf(q2[1], kvx[j].x, use_h ? qadd[1][rr - 1] : qadd[1][j]));
                    s[1] += e;
                    acc[1] = fmaf(e, kvx[j].y, acc[1]);
                }
            }
        }

        #pragma unroll
        for (int r = 0; r < 2; ++r)
            out[obase + (size_t)(h0 + r0 + r) * WW + tx] =
                acc[r] * __builtin_amdgcn_rcpf(s[r]);
    }
}

extern "C" void kernel_launch(void* const* d_in, const int* in_sizes, int n_in,
                              void* d_out, int out_size, void* d_ws, size_t ws_size,
                              hipStream_t stream) {
    const float* x     = (const float*)d_in[0];
    const float* wq    = (const float*)d_in[1];
    const float* wk    = (const float*)d_in[2];
    const float* wv    = (const float*)d_in[3];
    const float* rel_h = (const float*)d_in[4];
    const float* rel_w = (const float*)d_in[5];
    float* out = (float*)d_out;

    dim3 grid(HH / TRO, COUT / NCH, BB);       // (8, 16, 4) = 512 blocks
    fusedK<<<grid, 512, 0, stream>>>(x, wq, wk, wv, rel_h, rel_w, out);
}